// Round 2
// baseline (92.255 us; speedup 1.0000x reference)
//
#include <hip/hip_runtime.h>
#include <hip/hip_fp16.h>

// MinEuclideanDistBlock: out[b,n] = min_w sum_c sqrt(max(||win||^2 + ||shp||^2 - 2*cross, 0))
// B=64, C=3, L=2048, N=256, S=64, W=1985.
// R2 structure: bf16 MFMA 16x16x32; grid 1024 = (b=64) x (8 n-tiles of 32) x (2 w-halves of 1024);
// block = 4 waves (256 thr), wave tile 32w x 32n, ~32.5 KB LDS -> 4 blocks/CU.
// norms folded into MFMA acc-init as -(wv+ssq)/2 so acc_final = -d2/2; d = sqrt2*sqrt(max(-acc,0));
// sqrt2 applied once per output after the min. Cross-block min via u32 atomicMin (positive floats).

typedef float  v4f __attribute__((ext_vector_type(4)));
typedef short  v8s __attribute__((ext_vector_type(8)));
typedef unsigned short u16;
typedef unsigned int   u32;
typedef unsigned long long u64;

#define S_ 64
#define N_ 256
#define C_ 3
#define L_ 2048
#define W_ 1985
#define WL 1024      // w-range per block
#define NCH 274      // u64 chunks per shifted copy (1096 bf16 elements >= 1024+64, +pad)
#define THREADS 256
#define OUT_ELEMS 16384   // 64 * 256

__device__ __forceinline__ u16 f2bf(float f) {
    u32 u = __builtin_bit_cast(u32, f);
    return (u16)((u + 0x7FFFu + ((u >> 16) & 1u)) >> 16);
}
__device__ __forceinline__ float bf2f(u16 b) {
    return __builtin_bit_cast(float, ((u32)b) << 16);
}

__global__ __launch_bounds__(256)
void init_out_kernel(u32* __restrict__ out_u) {
    int i = blockIdx.x * 256 + threadIdx.x;
    if (i < OUT_ELEMS) out_u[i] = 0x7F800000u;   // +inf
}

__global__ __launch_bounds__(THREADS, 4)
void shapelet_min_kernel(const float* __restrict__ x,
                         const float* __restrict__ shp,
                         u32* __restrict__ out_u)
{
    __shared__ u64 xcopy[C_][4][NCH];     // 26304 B: 4 shifted bf16 copies of x[b,c,wstart:wstart+1088]
    __shared__ __half hwq[C_][WL];        //  6144 B: -0.5 * sliding window sq-norms (fp16)

    const int tid  = threadIdx.x;
    const int wave = tid >> 6;
    const int lane = tid & 63;
    const int m    = lane & 15;      // MFMA row/col within 16
    const int q    = lane >> 4;      // quad id 0..3
    const int wh   = blockIdx.x & 1;
    const int nb   = (blockIdx.x >> 1) & 7;
    const int b    = blockIdx.x >> 4;
    const int n0   = nb << 5;        // 32-wide n tile
    const int wstart = wh * WL;

    //=== Phase A: stage this block's 32-shapelet tile (bf16) into scratch (aliases xcopy) ===
    u16* scratch = (u16*)&xcopy[0][0][0];    // [C_][32][72] u16 = 13824 B
    #pragma unroll
    for (int k = 0; k < 6; ++k) {
        int idx = tid + k * THREADS;         // 1536 float4-groups: (c, n, sq)
        int sq = idx & 15;
        int n  = (idx >> 4) & 31;
        int c  = idx >> 9;
        v4f v = *(const v4f*)(shp + ((size_t)(c * N_ + n0 + n) * S_ + (sq << 2)));
        u64 pk = (u64)f2bf(v[0]) | ((u64)f2bf(v[1]) << 16)
               | ((u64)f2bf(v[2]) << 32) | ((u64)f2bf(v[3]) << 48);
        *(u64*)(scratch + ((c * 32 + n) * 72 + (sq << 2))) = pk;
    }
    __syncthreads();

    // B fragments -> registers (loop-invariant over w) + hs = -0.5*||shp||^2 per lane's n
    v8s   bfr[C_][2][2];
    float hs[C_][2];
    #pragma unroll
    for (int c = 0; c < C_; ++c) {
        #pragma unroll
        for (int nt = 0; nt < 2; ++nt) {
            float sacc = 0.f;
            #pragma unroll
            for (int h = 0; h < 2; ++h) {
                v8s f = *(const v8s*)(scratch + ((c * 32 + nt * 16 + m) * 72 + h * 32 + q * 8));
                bfr[c][nt][h] = f;
                #pragma unroll
                for (int j = 0; j < 8; ++j) {
                    float e = bf2f((u16)f[j]);
                    sacc += e * e;
                }
            }
            sacc += __shfl_xor(sacc, 16);
            sacc += __shfl_xor(sacc, 32);
            hs[c][nt] = -0.5f * sacc;        // per-lane n = n0 + nt*16 + m
        }
    }
    __syncthreads();

    //=== Phase B: build 4 shifted bf16 copies of x[b, :, wstart:] (copy r starts at wstart+r) ===
    {
        const float* xb = x + (size_t)b * (C_ * L_);
        #pragma unroll
        for (int k = 0; k < 4; ++k) {
            int gi = tid + k * THREADS;
            if (gi < C_ * NCH) {             // 822 groups of 4 elements
                int c = gi / NCH;
                int t = gi - c * NCH;
                int e = t << 2;              // local element index (global = wstart + e)
                int ge = wstart + e;
                float f[4];
                if (ge + 3 < L_) {
                    v4f v = *(const v4f*)(xb + c * L_ + ge);
                    f[0] = v[0]; f[1] = v[1]; f[2] = v[2]; f[3] = v[3];
                } else {
                    #pragma unroll
                    for (int i = 0; i < 4; ++i)
                        f[i] = (ge + i < L_) ? xb[c * L_ + ge + i] : 0.f;
                }
                u16 u[4];
                #pragma unroll
                for (int i = 0; i < 4; ++i) u[i] = f2bf(f[i]);
                #pragma unroll
                for (int r = 0; r < 4; ++r) {
                    u16* cp = (u16*)&xcopy[c][r][0];
                    #pragma unroll
                    for (int i = 0; i < 4; ++i) {
                        int pos = e + i - r;          // local elem j sits at index j-r in copy r
                        if (pos >= 0) cp[pos] = u[i];
                    }
                }
            }
        }
    }
    __syncthreads();

    //=== hw = -0.5 * sliding sum of squares (from bf16 copy 0), fp32 accumulate, fp16 store ===
    #pragma unroll
    for (int c = 0; c < C_; ++c) {
        const u64* cp0 = &xcopy[c][0][0];
        float e[68];
        #pragma unroll
        for (int kk = 0; kk < 17; ++kk) {
            u64 ch = cp0[tid + kk];
            e[kk * 4 + 0] = bf2f((u16)(ch));
            e[kk * 4 + 1] = bf2f((u16)(ch >> 16));
            e[kk * 4 + 2] = bf2f((u16)(ch >> 32));
            e[kk * 4 + 3] = bf2f((u16)(ch >> 48));
        }
        float s0 = 0.f;
        #pragma unroll
        for (int i = 0; i < 64; ++i) s0 += e[i] * e[i];
        float s1 = s0 - e[0] * e[0] + e[64] * e[64];
        float s2 = s1 - e[1] * e[1] + e[65] * e[65];
        float s3 = s2 - e[2] * e[2] + e[66] * e[66];
        union { u64 u; __half h[4]; } hp;
        hp.h[0] = __float2half(-0.5f * s0); hp.h[1] = __float2half(-0.5f * s1);
        hp.h[2] = __float2half(-0.5f * s2); hp.h[3] = __float2half(-0.5f * s3);
        *(u64*)&hwq[c][tid << 2] = hp.u;
    }
    __syncthreads();

    //=== Main loop: 8 iters x (wave tile 32w x 32n); acc init = hw + hs so acc_final = -d2/2 ===
    float mins[2] = {1e30f, 1e30f};

    #pragma unroll 1
    for (int it = 0; it < 8; ++it) {
        const int wb = it * 128 + wave * 32;           // local w base for this wave
        if (wstart + wb >= W_) continue;               // whole-wave invalid (uniform)

        float sums[2][2][4];
        #pragma unroll
        for (int mt = 0; mt < 2; ++mt)
            #pragma unroll
            for (int nt = 0; nt < 2; ++nt)
                #pragma unroll
                for (int g = 0; g < 4; ++g) sums[mt][nt][g] = 0.f;

        #pragma unroll
        for (int c = 0; c < C_; ++c) {
            // acc init from LDS hw (per mt, per g) + register hs (per nt)
            v4f acc[2][2];
            #pragma unroll
            for (int mt = 0; mt < 2; ++mt) {
                union { u64 u; __half h4[4]; } wq;
                wq.u = *(const u64*)&hwq[c][wb + mt * 16 + q * 4];
                #pragma unroll
                for (int g = 0; g < 4; ++g) {
                    float hv = __half2float(wq.h4[g]);
                    acc[mt][0][g] = hv + hs[c][0];
                    acc[mt][1][g] = hv + hs[c][1];
                }
            }
            // K-loop: two halves of S=64
            #pragma unroll
            for (int h = 0; h < 2; ++h) {
                v8s afr[2];
                #pragma unroll
                for (int mt = 0; mt < 2; ++mt) {
                    int p0 = wb + mt * 16 + m + h * 32 + q * 8;
                    int r  = m & 3;
                    int T  = (p0 - r) >> 2;
                    const u64* cp = &xcopy[c][r][0];
                    union { u64 u[2]; v8s v; } tmp;
                    tmp.u[0] = cp[T];
                    tmp.u[1] = cp[T + 1];
                    afr[mt] = tmp.v;
                }
                #pragma unroll
                for (int mt = 0; mt < 2; ++mt)
                    #pragma unroll
                    for (int nt = 0; nt < 2; ++nt)
                        acc[mt][nt] = __builtin_amdgcn_mfma_f32_16x16x32_bf16(
                            afr[mt], bfr[c][nt][h], acc[mt][nt], 0, 0, 0);
            }
            // epilogue: acc = -d2/2; d/sqrt2 = sqrt(max(-acc,0)); accumulate over channels
            #pragma unroll
            for (int mt = 0; mt < 2; ++mt)
                #pragma unroll
                for (int nt = 0; nt < 2; ++nt)
                    #pragma unroll
                    for (int g = 0; g < 4; ++g)
                        sums[mt][nt][g] += __builtin_amdgcn_sqrtf(fmaxf(-acc[mt][nt][g], 0.f));
        }
        // fold into running min over w (mask invalid padded windows)
        #pragma unroll
        for (int mt = 0; mt < 2; ++mt) {
            #pragma unroll
            for (int g = 0; g < 4; ++g) {
                bool ok = (wstart + wb + mt * 16 + q * 4 + g) < W_;
                #pragma unroll
                for (int nt = 0; nt < 2; ++nt) {
                    float vv = ok ? sums[mt][nt][g] : 1e30f;
                    mins[nt] = fminf(mins[nt], vv);
                }
            }
        }
    }

    //=== Reduce across quads (same n, different w-rows), then atomicMin to global ===
    #pragma unroll
    for (int nt = 0; nt < 2; ++nt) {
        mins[nt] = fminf(mins[nt], __shfl_xor(mins[nt], 16));
        mins[nt] = fminf(mins[nt], __shfl_xor(mins[nt], 32));
    }
    if (lane < 16) {
        #pragma unroll
        for (int nt = 0; nt < 2; ++nt) {
            float v = mins[nt] * 1.41421356237f;     // restore the sqrt(2) scale
            atomicMin(out_u + ((size_t)b * N_ + n0 + nt * 16 + m), __float_as_uint(v));
        }
    }
}

extern "C" void kernel_launch(void* const* d_in, const int* in_sizes, int n_in,
                              void* d_out, int out_size, void* d_ws, size_t ws_size,
                              hipStream_t stream) {
    const float* x   = (const float*)d_in[0];   // (64, 3, 2048) fp32
    const float* shp = (const float*)d_in[1];   // (3, 256, 64) fp32
    u32* out_u       = (u32*)d_out;             // (64, 1, 256) fp32, min'd via u32 atomicMin

    hipLaunchKernelGGL(init_out_kernel, dim3((OUT_ELEMS + 255) / 256), dim3(256), 0, stream, out_u);
    hipLaunchKernelGGL(shapelet_min_kernel, dim3(1024), dim3(THREADS), 0, stream,
                       x, (const float*)shp, out_u);
}